// Round 8
// baseline (255.226 us; speedup 1.0000x reference)
//
#include <hip/hip_runtime.h>

#define B_ 2
#define T_ 2048
#define H_ 1024
#define D_ 64
#define M_ 16
#define BT_ (B_*T_)

#define N_HID (B_*T_*H_)          // 4194304
#define N_W   (M_*H_*D_)          // 1048576
#define N_OW  (M_*D_*H_)          // 1048576
#define N_C   (N_HID + N_OW + 16) // canon: hid + ow + gates

#define OUT_SHA  (B_*T_*H_)       // 4194304
#define OUT_LOG  (2*B_*T_*H_)     // 8388608
#define OUT_MASK (OUT_LOG + B_*M_)
#define OUT_FBC  (OUT_MASK + B_*M_)

typedef __bf16 bf16x8 __attribute__((ext_vector_type(8)));
typedef float floatx4 __attribute__((ext_vector_type(4)));
typedef float floatx16 __attribute__((ext_vector_type(16)));
typedef unsigned int uintx4 __attribute__((ext_vector_type(4)));

__device__ __forceinline__ float bf2f(unsigned short u){
  unsigned int v = ((unsigned int)u) << 16;
  return __builtin_bit_cast(float, v);
}
__device__ __forceinline__ unsigned short f2bfn(float f){
  __bf16 h = (__bf16)f;                       // RNE
  return __builtin_bit_cast(unsigned short, h);
}
__device__ __forceinline__ unsigned int pk2bf(float a, float b){
  return (unsigned int)f2bfn(a) | ((unsigned int)f2bfn(b) << 16);
}
__device__ __forceinline__ void store_out(void* out, int flag, long idx, float v){
  if(flag) ((unsigned short*)out)[idx] = f2bfn(v);
  else     ((float*)out)[idx] = v;
}

// ---------------------------------------------------------------------------
// Kernel 0: dtype detector + aff zero.
// ---------------------------------------------------------------------------
__global__ void detect_kernel(const unsigned int* __restrict__ hid_words,
                              int* __restrict__ flag, double* __restrict__ aff){
  __shared__ int cnt[256];
  int c = 0;
  for(int i = threadIdx.x; i < 4096; i += 256){
    unsigned int e = (hid_words[i] >> 7) & 0xFFu;
    c += (e >= 96u && e <= 144u);
  }
  cnt[threadIdx.x] = c;
  __syncthreads();
  for(int s = 128; s > 0; s >>= 1){
    if(threadIdx.x < s) cnt[threadIdx.x] += cnt[threadIdx.x + s];
    __syncthreads();
  }
  if(threadIdx.x == 0) *flag = (cnt[0] > 2048) ? 1 : 0;
  if(threadIdx.x < B_*M_) aff[threadIdx.x] = 0.0;
}

// ---------------------------------------------------------------------------
// Kernel 0.5: canonicalize hid + o_weights + gates to bf16 in ws.
// ---------------------------------------------------------------------------
__global__ __launch_bounds__(256) void convert_kernel(
    const void* __restrict__ p0, const void* __restrict__ p4,
    const void* __restrict__ p5, const int* __restrict__ flagp,
    unsigned short* __restrict__ canon)
{
  long i4 = (long)(blockIdx.x*256 + threadIdx.x) * 4;
  if(i4 >= N_C) return;
  const void* src; long off;
  if(i4 < N_HID)            { src=p0; off=i4; }
  else if(i4 < N_HID+N_OW)  { src=p4; off=i4-N_HID; }
  else                      { src=p5; off=i4-N_HID-N_OW; }
  unsigned long long r;
  if(*flagp){
    r = *reinterpret_cast<const unsigned long long*>((const unsigned short*)src + off);
  } else {
    const float* f = (const float*)src + off;
    unsigned long long a = f2bfn(f[0]), b = f2bfn(f[1]), c = f2bfn(f[2]), d = f2bfn(f[3]);
    r = a | (b<<16) | (c<<32) | (d<<48);
  }
  *reinterpret_cast<unsigned long long*>(canon + i4) = r;
}

// ---------------------------------------------------------------------------
// Kernel 0.75: transpose wq/wk/wv -> WT[(m*3+p)][d][k] bf16
// ---------------------------------------------------------------------------
__global__ __launch_bounds__(256) void wtrans_kernel(
    const void* __restrict__ p1, const void* __restrict__ p2,
    const void* __restrict__ p3, const int* __restrict__ flagp,
    unsigned short* __restrict__ WT)
{
  __shared__ __align__(16) unsigned short Tb[64*72];
  const int x = blockIdx.x;            // 48 = p(3) x ktile(16)
  const int m = blockIdx.y;
  const int p = x >> 4, kt = x & 15;
  const void* src = (p==0) ? p1 : (p==1) ? p2 : p3;
  const int tid = threadIdx.x;
  const int kr = tid >> 2, dc = (tid & 3) * 16;
  long off = ((long)m*H_ + kt*64 + kr)*D_ + dc;
  if(*flagp){
    const unsigned short* s = (const unsigned short*)src + off;
    *reinterpret_cast<uintx4*>(&Tb[kr*72+dc])   = *reinterpret_cast<const uintx4*>(s);
    *reinterpret_cast<uintx4*>(&Tb[kr*72+dc+8]) = *reinterpret_cast<const uintx4*>(s+8);
  } else {
    const float* f = (const float*)src + off;
    #pragma unroll
    for(int j=0;j<8;j++){
      unsigned int w = pk2bf(f[2*j], f[2*j+1]);
      *reinterpret_cast<unsigned int*>(&Tb[kr*72+dc+2*j]) = w;
    }
  }
  __syncthreads();
  const int dr = tid >> 2, kc = (tid & 3) * 16;
  uintx4 o0, o1;
  #pragma unroll
  for(int j=0;j<4;j++){
    o0[j] = (unsigned int)Tb[(kc+2*j  )*72+dr] | ((unsigned int)Tb[(kc+2*j+1)*72+dr]<<16);
    o1[j] = (unsigned int)Tb[(kc+8+2*j)*72+dr] | ((unsigned int)Tb[(kc+9+2*j)*72+dr]<<16);
  }
  unsigned short* dst = WT + ((long)(m*3+p)*D_ + dr)*H_ + kt*64 + kc;
  *reinterpret_cast<uintx4*>(dst)   = o0;
  *reinterpret_cast<uintx4*>(dst+8) = o1;
}

// ---------------------------------------------------------------------------
// Kernel 1: q,k,v projections. 128 rows x 192 cols (one expert) per block.
// ---------------------------------------------------------------------------
__global__ __launch_bounds__(256) void qkv_kernel(
    const unsigned short* __restrict__ hid,
    const unsigned short* __restrict__ WT,
    unsigned short* __restrict__ qo,
    unsigned short* __restrict__ ko,
    unsigned short* __restrict__ vT)
{
  __shared__ __align__(16) unsigned short Ab[128*72];     // [t][k]
  __shared__ __align__(16) unsigned short Wb[3][64*72];   // [d][k]

  const int m  = blockIdx.y;
  const int r0 = blockIdx.x * 128;
  const int b  = r0 >> 11;
  const int tl = r0 & (T_-1);
  const int tid = threadIdx.x;
  const int lane = tid & 63, wid = tid >> 6;
  const int lc = lane & 15, qd = lane >> 4;

  const unsigned short* WTm = WT + (long)m*3*D_*H_;

  floatx4 accq[4][2], acck[4][2], accv[4][2];
  #pragma unroll
  for(int nt=0;nt<4;nt++)
    #pragma unroll
    for(int ss=0;ss<2;ss++){ accq[nt][ss]=(floatx4)(0.f); acck[nt][ss]=(floatx4)(0.f); accv[nt][ss]=(floatx4)(0.f); }

  const int arow = tid >> 1, ak0 = (tid & 1) * 32;
  const int wd   = tid >> 2, wk0 = (tid & 3) * 16;

  for(int kk=0; kk<H_; kk+=64){
    __syncthreads();
    {
      const unsigned short* s = hid + (long)(r0+arow)*H_ + kk + ak0;
      #pragma unroll
      for(int j=0;j<4;j++)
        *reinterpret_cast<uintx4*>(&Ab[arow*72 + ak0 + j*8]) =
            *reinterpret_cast<const uintx4*>(s + j*8);
    }
    {
      #pragma unroll
      for(int p=0;p<3;p++){
        const unsigned short* s = WTm + ((long)p*D_ + wd)*H_ + kk + wk0;
        *reinterpret_cast<uintx4*>(&Wb[p][wd*72 + wk0])   = *reinterpret_cast<const uintx4*>(s);
        *reinterpret_cast<uintx4*>(&Wb[p][wd*72 + wk0+8]) = *reinterpret_cast<const uintx4*>(s+8);
      }
    }
    __syncthreads();
    #pragma unroll
    for(int kc=0;kc<2;kc++){
      bf16x8 a0 = *(const bf16x8*)&Ab[(wid*32      + lc)*72 + kc*32 + qd*8];
      bf16x8 a1 = *(const bf16x8*)&Ab[(wid*32 + 16 + lc)*72 + kc*32 + qd*8];
      #pragma unroll
      for(int nt=0;nt<4;nt++){
        bf16x8 bq = *(const bf16x8*)&Wb[0][(nt*16+lc)*72 + kc*32 + qd*8];
        accq[nt][0] = __builtin_amdgcn_mfma_f32_16x16x32_bf16(a0, bq, accq[nt][0],0,0,0);
        accq[nt][1] = __builtin_amdgcn_mfma_f32_16x16x32_bf16(a1, bq, accq[nt][1],0,0,0);
        bf16x8 bk = *(const bf16x8*)&Wb[1][(nt*16+lc)*72 + kc*32 + qd*8];
        acck[nt][0] = __builtin_amdgcn_mfma_f32_16x16x32_bf16(a0, bk, acck[nt][0],0,0,0);
        acck[nt][1] = __builtin_amdgcn_mfma_f32_16x16x32_bf16(a1, bk, acck[nt][1],0,0,0);
        bf16x8 bv = *(const bf16x8*)&Wb[2][(nt*16+lc)*72 + kc*32 + qd*8];
        accv[nt][0] = __builtin_amdgcn_mfma_f32_16x16x32_bf16(bv, a0, accv[nt][0],0,0,0);
        accv[nt][1] = __builtin_amdgcn_mfma_f32_16x16x32_bf16(bv, a1, accv[nt][1],0,0,0);
      }
    }
  }

  const long obase = (long)(b*M_+m)*T_ + tl;
  #pragma unroll
  for(int nt=0;nt<4;nt++)
    #pragma unroll
    for(int ss=0;ss<2;ss++)
      #pragma unroll
      for(int r=0;r<4;r++){
        int trow = wid*32 + ss*16 + qd*4 + r;
        qo[(obase + trow)*D_ + nt*16 + lc] = f2bfn(accq[nt][ss][r]);
        ko[(obase + trow)*D_ + nt*16 + lc] = f2bfn(acck[nt][ss][r]);
      }
  const long vbase = (long)(b*M_+m)*D_;
  #pragma unroll
  for(int nt=0;nt<4;nt++)
    #pragma unroll
    for(int ss=0;ss<2;ss++)
      #pragma unroll
      for(int r=0;r<4;r++){
        int d    = nt*16 + qd*4 + r;
        int tcol = wid*32 + ss*16 + lc;
        vT[(vbase + d)*T_ + tl + tcol] = f2bfn(accv[nt][ss][r]);
      }
}

// ---------------------------------------------------------------------------
// Kernel 2: flash attention, 32x32x16 MFMA. Block = 128 Q rows, 4 waves =
// (2 Q-halves) x (2 j-parities); per round stage a 128-j K/V slab, wave reads
// only its 64-j sub-tile. S^T = K*Q^T (A=K, B=Q) -> lane owns i = lane&31.
// P goes C-layout -> A-layout IN REGISTERS via shfl_xor(32) (no LDS P buffer).
// Partial (O,l,t) merge linearly across j-parities through LDS at the end.
// entropy = log l - (0.125*traw)/l.  LDS = 36 KB.
// ---------------------------------------------------------------------------
__global__ __launch_bounds__(256) void attn_kernel(
    const unsigned short* __restrict__ q,
    const unsigned short* __restrict__ k,
    const unsigned short* __restrict__ vT,
    unsigned short* __restrict__ shaC,
    void* __restrict__ out, const int* __restrict__ flagp,
    double* __restrict__ aff)
{
  __shared__ __align__(16) unsigned short Sm[4*64*72];    // 36 KB: K[2] + V[2]
  unsigned short* Kb = Sm;                    // [2][64][72]  (j-sub, j, d)
  unsigned short* Vb = Sm + 2*64*72;          // [2][64][72]  (j-sub, d, j)

  const int bm = blockIdx.y;
  const int b = bm >> 4, m = bm & 15;
  const int qt = blockIdx.x;                  // T/128 = 16 tiles
  const int tid = threadIdx.x;
  const int lane = tid & 63, wid = tid >> 6;
  const int il = lane & 31, hi = lane >> 5;
  const int qrow0 = (wid & 1) * 64;           // wave's Q-half
  const int jp    = wid >> 1;                 // wave's j-parity

  const unsigned short* qp = q  + (long)(bm*T_ + qt*128 + qrow0)*D_;
  const unsigned short* kp = k  + (long)bm*T_*D_;
  const unsigned short* vp = vT + (long)bm*D_*T_;

  // Q fragments (B-operand, 32x32x16): i = it*32+il, k(d) = dblk*16 + hi*8
  bf16x8 aq[2][4];
  #pragma unroll
  for(int it=0;it<2;it++)
    #pragma unroll
    for(int dblk=0;dblk<4;dblk++)
      aq[it][dblk] = *(const bf16x8*)&qp[(it*32+il)*D_ + dblk*16 + hi*8];

  floatx16 oacc[2][2];                        // [i-tile][d-tile]
  #pragma unroll
  for(int it=0;it<2;it++)
    #pragma unroll
    for(int dt=0;dt<2;dt++) oacc[it][dt] = (floatx16)(0.0f);
  double ld[2] = {0,0}, td[2] = {0,0};

  const int kj  = tid >> 1, kc0 = (tid & 1) * 32;   // K staging
  const int vd  = tid >> 2;                         // V staging: d row
  const int vsub= (tid >> 1) & 1;
  const int vj0 = (tid & 1) * 32;
  const float C2 = 0.1803368801f;             // 0.125 * log2(e)

  for(int r=0; r<16; r++){
    __syncthreads();
    { // stage K slab [j][d] and V slab [d][j]
      const unsigned short* ks = kp + (long)(r*128 + kj)*D_ + kc0;
      unsigned short* kd = &Kb[(kj>>6)*64*72 + (kj&63)*72 + kc0];
      #pragma unroll
      for(int j=0;j<4;j++)
        *reinterpret_cast<uintx4*>(kd + j*8) = *reinterpret_cast<const uintx4*>(ks + j*8);
      const unsigned short* vs = vp + (long)vd*T_ + r*128 + vsub*64 + vj0;
      unsigned short* vdst = &Vb[vsub*64*72 + vd*72 + vj0];
      #pragma unroll
      for(int j=0;j<4;j++)
        *reinterpret_cast<uintx4*>(vdst + j*8) = *reinterpret_cast<const uintx4*>(vs + j*8);
    }
    __syncthreads();

    const unsigned short* Kw = &Kb[jp*64*72];
    const unsigned short* Vw = &Vb[jp*64*72];

    #pragma unroll
    for(int jt=0; jt<2; jt++){
      // K frags (A-op): j = jt*32+il, k(d) = dblk*16 + hi*8
      bf16x8 kf[4];
      #pragma unroll
      for(int dblk=0;dblk<4;dblk++)
        kf[dblk] = *(const bf16x8*)&Kw[(jt*32+il)*72 + dblk*16 + hi*8];
      // V frags (B-op): d = dt*32+il, k(j) = (jt*2+jbl)*16 + hi*8
      bf16x8 vf[2][2];
      #pragma unroll
      for(int dt=0;dt<2;dt++)
        #pragma unroll
        for(int jbl=0;jbl<2;jbl++)
          vf[dt][jbl] = *(const bf16x8*)&Vw[(dt*32+il)*72 + (jt*2+jbl)*16 + hi*8];

      #pragma unroll
      for(int it=0; it<2; it++){
        floatx16 sa = (floatx16)(0.0f);
        #pragma unroll
        for(int dblk=0;dblk<4;dblk++)
          sa = __builtin_amdgcn_mfma_f32_32x32x16_bf16(kf[dblk], aq[it][dblk], sa,0,0,0);

        // lane holds i = it*32+il; j = (reg&3) + 8*(reg>>2) + 4*hi
        float lr = 0.f, tr = 0.f;
        unsigned int u[4][2];
        #pragma unroll
        for(int g=0; g<4; g++){
          float e0 = __builtin_amdgcn_exp2f(sa[4*g+0]*C2);
          float e1 = __builtin_amdgcn_exp2f(sa[4*g+1]*C2);
          float e2 = __builtin_amdgcn_exp2f(sa[4*g+2]*C2);
          float e3 = __builtin_amdgcn_exp2f(sa[4*g+3]*C2);
          lr += (e0+e1)+(e2+e3);
          tr = fmaf(e0, sa[4*g+0], tr); tr = fmaf(e1, sa[4*g+1], tr);
          tr = fmaf(e2, sa[4*g+2], tr); tr = fmaf(e3, sa[4*g+3], tr);
          u[g][0] = pk2bf(e0, e1);
          u[g][1] = pk2bf(e2, e3);
        }
        ld[it] += (double)lr; td[it] += (double)tr;

        // P C-layout -> A-layout: exchange with lane^32, build frags, PV MFMA
        #pragma unroll
        for(int jbl=0; jbl<2; jbl++){
          const int glo = 2*jbl, ghi = glo+1;
          unsigned s0 = hi ? u[glo][0] : u[ghi][0];
          unsigned s1 = hi ? u[glo][1] : u[ghi][1];
          unsigned r0 = __shfl_xor(s0, 32);
          unsigned r1 = __shfl_xor(s1, 32);
          uintx4 fu;
          fu[0] = hi ? r0 : u[glo][0];
          fu[1] = hi ? r1 : u[glo][1];
          fu[2] = hi ? u[ghi][0] : r0;
          fu[3] = hi ? u[ghi][1] : r1;
          bf16x8 pf = __builtin_bit_cast(bf16x8, fu);
          oacc[it][0] = __builtin_amdgcn_mfma_f32_32x32x16_bf16(pf, vf[0][jbl], oacc[it][0],0,0,0);
          oacc[it][1] = __builtin_amdgcn_mfma_f32_32x32x16_bf16(pf, vf[1][jbl], oacc[it][1],0,0,0);
        }
      }
    }
  }

  // ---- merge j-parities: waves 2,3 dump to LDS; waves 0,1 add ----
  __syncthreads();
  double* db = (double*)Sm;                   // 2 x 256 dbl (4 KB)
  float*  fb = (float*)Sm + 1024;             // 2 x 4096 f32 (32 KB)
  if(wid >= 2){
    const int rg = wid - 2;
    #pragma unroll
    for(int it=0;it<2;it++){
      db[rg*256 +       it*64 + lane] = ld[it];
      db[rg*256 + 128 + it*64 + lane] = td[it];
      #pragma unroll
      for(int dt=0;dt<2;dt++)
        #pragma unroll
        for(int rr=0;rr<16;rr++)
          fb[rg*4096 + ((it*2+dt)*16+rr)*64 + lane] = oacc[it][dt][rr];
    }
  }
  __syncthreads();
  if(wid < 2){
    const int rg = wid;
    #pragma unroll
    for(int it=0;it<2;it++){
      ld[it] += db[rg*256 +       it*64 + lane];
      td[it] += db[rg*256 + 128 + it*64 + lane];
      #pragma unroll
      for(int dt=0;dt<2;dt++)
        #pragma unroll
        for(int rr=0;rr<16;rr++)
          oacc[it][dt][rr] += fb[rg*4096 + ((it*2+dt)*16+rr)*64 + lane];
    }
    // complete l/t across hi halves (each row's two lane copies)
    #pragma unroll
    for(int it=0;it<2;it++){
      ld[it] += __shfl_xor(ld[it], 32);
      td[it] += __shfl_xor(td[it], 32);
    }
    double es = 0.0;
    #pragma unroll
    for(int it=0;it<2;it++) es += log(ld[it]) - 0.125*td[it]/ld[it];
    es += __shfl_xor(es, 1); es += __shfl_xor(es, 2);
    es += __shfl_xor(es, 4); es += __shfl_xor(es, 8); es += __shfl_xor(es, 16);
    if(lane == 0) atomicAdd(&aff[bm], es);

    const int flag = *flagp;
    #pragma unroll
    for(int it=0;it<2;it++){
      float lf = (float)ld[it];
      float linv[16];
      #pragma unroll
      for(int rr=0;rr<16;rr++)
        linv[rr] = 1.0f / __shfl(lf, (rr&3) + 8*(rr>>2) + 4*hi);
      #pragma unroll
      for(int dt=0;dt<2;dt++)
        #pragma unroll
        for(int rr=0;rr<16;rr++){
          int i = it*32 + (rr&3) + 8*(rr>>2) + 4*hi;
          int d = dt*32 + il;
          int trow_ = qt*128 + qrow0 + i;
          float sval = oacc[it][dt][rr] * linv[rr];
          long idx = ((long)(b*T_ + trow_)*M_ + m)*D_ + d;
          shaC[idx] = f2bfn(sval);
          store_out(out, flag, OUT_SHA + idx, sval);
        }
    }
  }
}

// ---------------------------------------------------------------------------
// Kernel 3: gating, 32 parallel lanes (one per b,m), fp64.
// ---------------------------------------------------------------------------
__global__ void gate_kernel(const double* __restrict__ aff_sum,
                            const unsigned short* __restrict__ gates,
                            void* __restrict__ out, const int* __restrict__ flagp,
                            float* __restrict__ nmask)
{
  const int tid = threadIdx.x;
  if(tid >= 32) return;
  const int b = tid >> 4, m = tid & 15;
  const int flag = *flagp;

  double a = -aff_sum[b*M_+m] / (double)T_;
  double s = a;
  s += __shfl_xor(s,1); s += __shfl_xor(s,2); s += __shfl_xor(s,4); s += __shfl_xor(s,8);
  double mu = s / 16.0;
  double dd = a - mu;
  double v = dd*dd;
  v += __shfl_xor(v,1); v += __shfl_xor(v,2); v += __shfl_xor(v,4); v += __shfl_xor(v,8);
  double sd = sqrt(v / 15.0);
  double z = dd / (sd + 1e-9);
  double g = (double)bf2f(gates[m]);
  double pre = z - 1.0/(1.0 + exp(-g));
  store_out(out, flag, OUT_LOG + b*M_+m, (float)pre);

  int act = (pre > 0.0);
  unsigned long long bal = __ballot(act);
  int nact = __popcll((bal >> (b*16)) & 0xFFFFull);

  double mask;
  if(nact > 0){
    mask = act ? 1.0 : 0.0;
  } else {
    double m1 = z, m2 = -1e300;
    #pragma unroll
    for(int d2=1; d2<16; d2<<=1){
      double o1 = __shfl_xor(m1, d2), o2 = __shfl_xor(m2, d2);
      if(o1 > m1){ m2 = fmax(m1, o2); m1 = o1; }
      else       { m2 = fmax(m2, o1); }
    }
    mask = (z >= m2) ? 1.0 : 0.0;
  }
  int nsel = (nact > 0) ? nact : 2;
  store_out(out, flag, OUT_MASK + b*M_+m, (float)mask);
  nmask[b*M_+m] = (float)(mask / (double)nsel);

  unsigned long long fb = __ballot((nact==0) && (m==0));
  if(tid == 0) store_out(out, flag, OUT_FBC, (float)__popcll(fb));
}

// ---------------------------------------------------------------------------
// Kernel 4: dynO[b,d,h] = sum_m nm[b,m]*o_w[m,d,h]
// ---------------------------------------------------------------------------
__global__ __launch_bounds__(256) void oproj_kernel(
    const unsigned short* __restrict__ ow, const float* __restrict__ nmask,
    float* __restrict__ dynO)
{
  int idx = blockIdx.x*256 + threadIdx.x;
  int b = idx >> 16;
  int dh = idx & 65535;
  float acc = 0.f;
  #pragma unroll
  for(int m=0;m<M_;m++) acc += nmask[b*M_+m]*bf2f(ow[m*D_*H_ + dh]);
  dynO[idx] = acc;
}

// ---------------------------------------------------------------------------
// Kernel 5: combined = sum_m nm*sha; final = combined x dynO.
// ---------------------------------------------------------------------------
__global__ __launch_bounds__(256) void final_kernel(
    const unsigned short* __restrict__ shaC, const float* __restrict__ nmask,
    const float* __restrict__ dynO, void* __restrict__ out,
    const int* __restrict__ flagp)
{
  __shared__ float combT[64][36];       // [d][tt], padded
  const int bx = blockIdx.x;            // 128 = b(2) x ttile(64)
  const int b  = bx >> 6;
  const int t0 = (bx & 63) * 32;
  const int h  = blockIdx.y*256 + threadIdx.x;
  const int tid = threadIdx.x;

  float nm[M_];
  #pragma unroll
  for(int m=0;m<M_;m++) nm[m] = nmask[b*M_+m];

  #pragma unroll
  for(int pass=0;pass<8;pass++){
    int idx = pass*256 + tid;
    int d = idx & 63, tt = idx >> 6;
    const unsigned short* sp = shaC + ((long)(b*T_ + t0 + tt)*M_)*D_ + d;
    float a = 0.f;
    #pragma unroll
    for(int m=0;m<M_;m++) a = fmaf(nm[m], bf2f(sp[m*D_]), a);
    combT[d][tt] = a;
  }
  __syncthreads();

  float acc[32];
  #pragma unroll
  for(int tt=0;tt<32;tt++) acc[tt] = 0.f;
  for(int d=0; d<64; d++){
    float g = dynO[((long)b*D_ + d)*H_ + h];
    const floatx4* cp = reinterpret_cast<const floatx4*>(&combT[d][0]);
    #pragma unroll
    for(int c8=0;c8<8;c8++){
      floatx4 cv = cp[c8];
      #pragma unroll
      for(int r=0;r<4;r++) acc[c8*4+r] = fmaf(cv[r], g, acc[c8*4+r]);
    }
  }
  const int flag = *flagp;
  #pragma unroll
  for(int tt=0;tt<32;tt++)
    store_out(out, flag, (long)(b*T_ + t0 + tt)*H_ + h, acc[tt]);
}

// ---------------------------------------------------------------------------
extern "C" void kernel_launch(void* const* d_in, const int* in_sizes, int n_in,
                              void* d_out, int out_size, void* d_ws, size_t ws_size,
                              hipStream_t stream)
{
  (void)in_sizes; (void)n_in; (void)out_size; (void)ws_size;
  char* ws = (char*)d_ws;
  int*    flag  = (int*)(ws);
  double* aff   = (double*)(ws + 64);
  float*  nmask = (float*)(ws + 512);
  float*  dynO  = (float*)(ws + 4096);                        // 512 KB
  unsigned short* canon = (unsigned short*)(ws + (1u<<20));
  unsigned short* c_hid = canon;
  unsigned short* c_ow  = c_hid + N_HID;
  unsigned short* c_gt  = c_ow + N_OW;
  unsigned short* WT    = (unsigned short*)(ws + (size_t)12*1024*1024);
  unsigned short* qb    = (unsigned short*)(ws + (size_t)18*1024*1024);
  unsigned short* kb    = qb + (size_t)B_*M_*T_*D_;
  unsigned short* vT    = kb + (size_t)B_*M_*T_*D_;
  unsigned short* shaC  = vT + (size_t)B_*M_*T_*D_;

  detect_kernel <<<1, 256, 0, stream>>>((const unsigned int*)d_in[0], flag, aff);
  convert_kernel<<<(N_C/4 + 255)/256, 256, 0, stream>>>(
      d_in[0], d_in[4], d_in[5], flag, canon);
  wtrans_kernel <<<dim3(48, 16),     256, 0, stream>>>(d_in[1], d_in[2], d_in[3], flag, WT);
  qkv_kernel    <<<dim3(BT_/128, M_),256, 0, stream>>>(c_hid, WT, qb, kb, vT);
  attn_kernel   <<<dim3(T_/128, B_*M_),256,0, stream>>>(qb, kb, vT, shaC, d_out, flag, aff);
  gate_kernel   <<<1, 64, 0, stream>>>(aff, c_gt, d_out, flag, nmask);
  oproj_kernel  <<<512, 256, 0, stream>>>(c_ow, nmask, dynO);
  final_kernel  <<<dim3(128, 4), 256, 0, stream>>>(shaC, nmask, dynO, d_out, flag);
}